// Round 2
// baseline (249.298 us; speedup 1.0000x reference)
//
#include <hip/hip_runtime.h>

typedef __attribute__((ext_vector_type(8))) short bhalf8;
typedef __attribute__((ext_vector_type(4))) float floatx4;

#define NF 6  // freq_list = [1,103,205,307,409,511] -> periods [2,104,206,308,410,512]

__device__ __forceinline__ unsigned short f2bf(float f) {
  unsigned u = __float_as_uint(f);
  u += 0x7FFFu + ((u >> 16) & 1u);
  return (unsigned short)(u >> 16);
}

// ---------------- kernel 1: period weights (6-freq DFT + softmax) ----------
__global__ __launch_bounds__(384) void pw_kernel(const float* __restrict__ x,
                                                 float* __restrict__ pwbuf) {
  const int bh = blockIdx.x;
  const int tid = threadIdx.x;
  const int k = tid >> 6;        // 0..5 (one wave per frequency)
  const int f = tid & 63;
  const int freq = 1 + 102 * k;  // {1,103,205,307,409,511}
  const float* xb = x + (size_t)bh * (1024 * 64) + f;
  float re = 0.f, im = 0.f;
  for (int t = 0; t < 1024; ++t) {
    float v = xb[(size_t)t * 64];
    int ph = (freq * t) & 1023;  // exact: phase has period 1024
    float ang = -6.283185307179586f * ((float)ph * (1.0f / 1024.0f));
    float s, c;
    __sincosf(ang, &s, &c);
    re = fmaf(v, c, re);
    im = fmaf(v, s, im);
  }
  float amp = sqrtf(re * re + im * im);
#pragma unroll
  for (int off = 32; off > 0; off >>= 1) amp += __shfl_xor(amp, off);
  __shared__ float samp[NF];
  if (f == 0) samp[k] = amp * (1.0f / 64.0f);  // mean over F
  __syncthreads();
  if (tid == 0) {
    float m = samp[0];
#pragma unroll
    for (int i = 1; i < NF; ++i) m = fmaxf(m, samp[i]);
    float e[NF], s = 0.f;
#pragma unroll
    for (int i = 0; i < NF; ++i) { e[i] = __expf(samp[i] - m); s += e[i]; }
    float inv = 1.0f / s;
#pragma unroll
    for (int i = 0; i < NF; ++i) pwbuf[bh * NF + i] = e[i] * inv;
  }
}

// ---------------- kernel 2: W -> transposed + pre-swizzled bf16 LDS image --
// wt_img[didj] is the exact 8KB LDS image: row fo (128B), phys chunk c (16B)
// holds Wt[fo][ (c ^ (fo&7))*8 .. +8 ] where Wt[fo][fi] = W[didj][fi][fo].
__global__ void prep_w(const float* __restrict__ W,
                       unsigned short* __restrict__ wt_img) {
  int task = blockIdx.x * 256 + threadIdx.x;  // 9*64*8 = 4608 tasks
  int didj = task >> 9;
  int fo = (task >> 3) & 63;
  int c = task & 7;
  int cs = c ^ (fo & 7);
  bhalf8 pk;
#pragma unroll
  for (int j = 0; j < 8; ++j) {
    int fi = cs * 8 + j;
    pk[j] = (short)f2bf(W[(size_t)(didj * 64 + fi) * 64 + fo]);
  }
  *(bhalf8*)((char*)wt_img + (size_t)didj * 8192 + fo * 128 + c * 16) = pk;
}

// ---------------- kernel 3: fused 6-period conv + relu + weighted sum + x --
__global__ __launch_bounds__(256, 2) void conv_kernel(
    const float* __restrict__ x, const unsigned short* __restrict__ wt_img,
    const float* __restrict__ bias, const float* __restrict__ pwbuf,
    float* __restrict__ out) {
  __shared__ __align__(16) unsigned short strips[3 * 132 * 64];  // 50688 B
  __shared__ __align__(16) unsigned short wlds[64 * 64];         // 8192 B

  const int tid = threadIdx.x;
  const int bh = blockIdx.y;
  const int t0 = blockIdx.x * 128;
  const int l15 = tid & 15;
  const int l4 = (tid >> 4) & 3;
  const int wid = tid >> 6;
  const int wm = wid * 32;  // wave tile: rows [wm, wm+32) x all 64 cols

  const float* xbh = x + (size_t)bh * (1024 * 64);

  float bv[4];
#pragma unroll
  for (int nt = 0; nt < 4; ++nt) bv[nt] = bias[nt * 16 + l15];

  floatx4 fin[2][4];
#pragma unroll
  for (int mt = 0; mt < 2; ++mt)
#pragma unroll
    for (int nt = 0; nt < 4; ++nt) fin[mt][nt] = (floatx4)0.0f;

#pragma unroll 1
  for (int kp = 0; kp < NF; ++kp) {
    const int q = (kp == 0) ? 512 : (kp == 1) ? 10 : (kp == 2) ? 5
                  : (kp == 3) ? 4 : (kp == 4) ? 3 : 2;

    __syncthreads();  // previous kp's strip readers done
    // ---- stage 3 halo strips: strip di row trel <-> t' = t0+(di-1)q-1+trel
#pragma unroll
    for (int di = 0; di < 3; ++di) {
      int tbase = t0 + (di - 1) * q - 1;
#pragma unroll
      for (int rr = 0; rr < 5; ++rr) {
        int trel = (tid >> 3) + rr * 32;
        if (trel < 130) {
          int tp = tbase + trel;
          int fi0 = (tid & 7) * 8;
          float va[8];
          if ((unsigned)tp < 1024u) {
            const float4* src = (const float4*)(xbh + (size_t)tp * 64 + fi0);
            float4 u0 = src[0], u1 = src[1];
            va[0] = u0.x; va[1] = u0.y; va[2] = u0.z; va[3] = u0.w;
            va[4] = u1.x; va[5] = u1.y; va[6] = u1.z; va[7] = u1.w;
          } else {
#pragma unroll
            for (int j = 0; j < 8; ++j) va[j] = 0.f;
          }
          bhalf8 pk;
#pragma unroll
          for (int j = 0; j < 8; ++j) pk[j] = (short)f2bf(va[j]);
          int row = di * 132 + trel;
          *(bhalf8*)((char*)strips + (row << 7) +
                     ((fi0 * 2) ^ ((trel & 7) << 4))) = pk;
        }
      }
    }

    // per-output-row column validity (j' = j+dj-1 in [0,q))
    int jm0 = (t0 + wm + l15) % q;
    int jm1 = (t0 + wm + 16 + l15) % q;

    floatx4 acc[2][4];
#pragma unroll
    for (int mt = 0; mt < 2; ++mt)
#pragma unroll
      for (int nt = 0; nt < 4; ++nt) acc[mt][nt] = (floatx4)0.0f;

#pragma unroll
    for (int di = 0; di < 3; ++di) {
#pragma unroll
      for (int dj = 0; dj < 3; ++dj) {
        __syncthreads();  // protect wlds (and, 1st iter, strips staging)
        {  // stage 8KB pre-swizzled W tile for this (di,dj)
          const char* wsrc =
              (const char*)wt_img + (size_t)(di * 3 + dj) * 8192 + tid * 32;
          bhalf8 w0 = *(const bhalf8*)wsrc;
          bhalf8 w1 = *(const bhalf8*)(wsrc + 16);
          *(bhalf8*)((char*)wlds + tid * 32) = w0;
          *(bhalf8*)((char*)wlds + tid * 32 + 16) = w1;
        }
        __syncthreads();

        const bhalf8 zz = (bhalf8)0;
        bool m0ok = (dj == 0) ? (jm0 > 0) : (dj == 2) ? (jm0 < q - 1) : true;
        bool m1ok = (dj == 0) ? (jm1 > 0) : (dj == 2) ? (jm1 < q - 1) : true;
#pragma unroll
        for (int kk = 0; kk < 2; ++kk) {
          int kb = kk * 64 + l4 * 16;  // byte offset of this lane's k-chunk
          int trelA = wm + l15 + dj;   // mt=0 row in strip coords
          bhalf8 a0 = *(const bhalf8*)((const char*)strips +
                                       ((di * 132 + trelA) << 7) +
                                       (kb ^ ((trelA & 7) << 4)));
          int trelB = trelA + 16;      // mt=1
          bhalf8 a1 = *(const bhalf8*)((const char*)strips +
                                       ((di * 132 + trelB) << 7) +
                                       (kb ^ ((trelB & 7) << 4)));
          if (!m0ok) a0 = zz;
          if (!m1ok) a1 = zz;
          bhalf8 bfr[4];
#pragma unroll
          for (int nt = 0; nt < 4; ++nt) {
            int fo = nt * 16 + l15;
            bfr[nt] = *(const bhalf8*)((const char*)wlds + (fo << 7) +
                                       (kb ^ ((fo & 7) << 4)));
          }
#pragma unroll
          for (int nt = 0; nt < 4; ++nt) {
            acc[0][nt] = __builtin_amdgcn_mfma_f32_16x16x32_bf16(
                a0, bfr[nt], acc[0][nt], 0, 0, 0);
            acc[1][nt] = __builtin_amdgcn_mfma_f32_16x16x32_bf16(
                a1, bfr[nt], acc[1][nt], 0, 0, 0);
          }
        }
      }
    }

    // epilogue: fin += pw * relu(conv + b)
    float pwv = pwbuf[bh * NF + kp];
#pragma unroll
    for (int mt = 0; mt < 2; ++mt)
#pragma unroll
      for (int nt = 0; nt < 4; ++nt)
#pragma unroll
        for (int r = 0; r < 4; ++r) {
          float y = acc[mt][nt][r] + bv[nt];
          y = fmaxf(y, 0.f);
          fin[mt][nt][r] += pwv * y;
        }
  }

  // write out + residual (C/D layout: col = lane&15, row = (lane>>4)*4 + r)
#pragma unroll
  for (int mt = 0; mt < 2; ++mt) {
#pragma unroll
    for (int nt = 0; nt < 4; ++nt) {
      int row = t0 + wm + mt * 16 + l4 * 4;
      int col = nt * 16 + l15;
      size_t base = ((size_t)bh * 1024 + row) * 64 + col;
#pragma unroll
      for (int r = 0; r < 4; ++r) {
        out[base + (size_t)r * 64] = fin[mt][nt][r] + x[base + (size_t)r * 64];
      }
    }
  }
}

extern "C" void kernel_launch(void* const* d_in, const int* in_sizes, int n_in,
                              void* d_out, int out_size, void* d_ws,
                              size_t ws_size, hipStream_t stream) {
  const float* x = (const float*)d_in[0];
  const float* W = (const float*)d_in[1];
  const float* b = (const float*)d_in[2];
  float* out = (float*)d_out;
  float* pwbuf = (float*)d_ws;                                    // 6144 B
  unsigned short* wt_img = (unsigned short*)((char*)d_ws + 8192); // 73728 B

  pw_kernel<<<dim3(256), dim3(384), 0, stream>>>(x, pwbuf);
  prep_w<<<dim3(18), dim3(256), 0, stream>>>(W, wt_img);
  conv_kernel<<<dim3(8, 256), dim3(256), 0, stream>>>(x, wt_img, b, pwbuf, out);
}

// Round 3
// 161.401 us; speedup vs baseline: 1.5446x; 1.5446x over previous
//
#include <hip/hip_runtime.h>

typedef __attribute__((ext_vector_type(8))) short bhalf8;
typedef __attribute__((ext_vector_type(4))) float floatx4;

#define NF 6  // freq_list = [1,103,205,307,409,511] -> periods [2,104,206,308,410,512]

__device__ __forceinline__ unsigned short f2bf(float f) {
  unsigned u = __float_as_uint(f);
  u += 0x7FFFu + ((u >> 16) & 1u);
  return (unsigned short)(u >> 16);
}

// ---------------- kernel 1: period weights (6-freq DFT + softmax) ----------
// 256 threads = 4 waves; wave w handles t in [w*256, w*256+256), lane = f.
// Per-freq complex rotation recurrence replaces per-t sincos.
__global__ __launch_bounds__(256) void pw_kernel(const float* __restrict__ x,
                                                 float* __restrict__ pwbuf) {
  const int bh = blockIdx.x;
  const int tid = threadIdx.x;
  const int w = tid >> 6;
  const int f = tid & 63;
  const int t0w = w * 256;
  const float* xb = x + (size_t)bh * 65536 + f;

  const float STEP = -6.283185307179586f / 1024.0f;
  float re[NF], im[NF], c[NF], s[NF], ck[NF], sk[NF];
#pragma unroll
  for (int k = 0; k < NF; ++k) {
    int freq = 1 + 102 * k;
    int ph0 = (freq * t0w) & 1023;
    __sincosf((float)ph0 * STEP, &s[k], &c[k]);
    __sincosf((float)freq * STEP, &sk[k], &ck[k]);
    re[k] = 0.f;
    im[k] = 0.f;
  }
#pragma unroll 4
  for (int t = 0; t < 256; ++t) {
    float v = xb[(size_t)(t0w + t) * 64];
#pragma unroll
    for (int k = 0; k < NF; ++k) {
      re[k] = fmaf(v, c[k], re[k]);
      im[k] = fmaf(v, s[k], im[k]);
      float cn = fmaf(c[k], ck[k], -s[k] * sk[k]);
      float sn = fmaf(c[k], sk[k], s[k] * ck[k]);
      c[k] = cn;
      s[k] = sn;
    }
  }
  __shared__ float part[4][NF][64][2];  // 12 KB
#pragma unroll
  for (int k = 0; k < NF; ++k) {
    part[w][k][f][0] = re[k];
    part[w][k][f][1] = im[k];
  }
  __syncthreads();
  if (tid < 64) {
    float sm[NF];
#pragma unroll
    for (int k = 0; k < NF; ++k) {
      float rr = 0.f, ii = 0.f;
#pragma unroll
      for (int ww = 0; ww < 4; ++ww) {
        rr += part[ww][k][tid][0];
        ii += part[ww][k][tid][1];
      }
      float amp = sqrtf(rr * rr + ii * ii);
#pragma unroll
      for (int off = 32; off > 0; off >>= 1) amp += __shfl_xor(amp, off);
      sm[k] = amp * (1.0f / 64.0f);
    }
    if (tid == 0) {
      float m = sm[0];
#pragma unroll
      for (int i = 1; i < NF; ++i) m = fmaxf(m, sm[i]);
      float e[NF], ssum = 0.f;
#pragma unroll
      for (int i = 0; i < NF; ++i) {
        e[i] = __expf(sm[i] - m);
        ssum += e[i];
      }
      float inv = 1.0f / ssum;
#pragma unroll
      for (int i = 0; i < NF; ++i) pwbuf[bh * NF + i] = e[i] * inv;
    }
  }
}

// ---------------- kernel 2: W -> transposed + pre-swizzled bf16 LDS image --
// wt_img[didj] is the exact 8KB LDS image: row fo (128B), phys chunk c (16B)
// holds Wt[fo][ (c ^ (fo&7))*8 .. +8 ] where Wt[fo][fi] = W[didj][fi][fo].
__global__ void prep_w(const float* __restrict__ W,
                       unsigned short* __restrict__ wt_img) {
  int task = blockIdx.x * 256 + threadIdx.x;  // 9*64*8 = 4608 tasks
  int didj = task >> 9;
  int fo = (task >> 3) & 63;
  int c = task & 7;
  int cs = c ^ (fo & 7);
  bhalf8 pk;
#pragma unroll
  for (int j = 0; j < 8; ++j) {
    int fi = cs * 8 + j;
    pk[j] = (short)f2bf(W[(size_t)(didj * 64 + fi) * 64 + fo]);
  }
  *(bhalf8*)((char*)wt_img + (size_t)didj * 8192 + fo * 128 + c * 16) = pk;
}

// ---------------- kernel 3: fused 6-period conv + relu + weighted sum + x --
// Stage-once / single-barrier design: 152-row near window covers all taps of
// kp>=1 (q<=10) and kp0's center di; one 132-row far strip covers kp0's valid
// off-center di (blocks never straddle t=512). All 9 W tiles resident in LDS.
// didj outer (B-frags in regs, amortized over 6 periods), kp inner (unrolled,
// acc[6][2][4] static-indexed).
__global__ __launch_bounds__(256, 1) void conv_kernel(
    const float* __restrict__ x, const unsigned short* __restrict__ wt_img,
    const float* __restrict__ bias, const float* __restrict__ pwbuf,
    float* __restrict__ out) {
  __shared__ __align__(16) unsigned short win[152 * 64];   // 19456 B
  __shared__ __align__(16) unsigned short farw[132 * 64];  // 16896 B
  __shared__ __align__(16) unsigned short wl[9 * 64 * 64]; // 73728 B

  const int tid = threadIdx.x;
  const int bh = blockIdx.y;
  const int t0 = blockIdx.x * 128;
  const float* xbh = x + (size_t)bh * (1024 * 64);

  // ---- stage near window: row trel <-> t' = t0 - 12 + trel
  {
    const int fi0 = (tid & 7) * 8;
#pragma unroll
    for (int rr = 0; rr < 5; ++rr) {
      int trel = (tid >> 3) + rr * 32;
      if (trel < 152) {
        int tp = t0 - 12 + trel;
        float va[8];
        if ((unsigned)tp < 1024u) {
          const float4* src = (const float4*)(xbh + (size_t)tp * 64 + fi0);
          float4 u0 = src[0], u1 = src[1];
          va[0] = u0.x; va[1] = u0.y; va[2] = u0.z; va[3] = u0.w;
          va[4] = u1.x; va[5] = u1.y; va[6] = u1.z; va[7] = u1.w;
        } else {
#pragma unroll
          for (int j = 0; j < 8; ++j) va[j] = 0.f;
        }
        bhalf8 pk;
#pragma unroll
        for (int j = 0; j < 8; ++j) pk[j] = (short)f2bf(va[j]);
        *(bhalf8*)((char*)win + (trel << 7) +
                   ((fi0 * 2) ^ ((trel & 7) << 4))) = pk;
      }
    }
    // ---- stage far strip: row trel <-> t' = fb + trel
    const int fb = (t0 < 512) ? (t0 + 510) : (t0 - 514);
#pragma unroll
    for (int rr = 0; rr < 5; ++rr) {
      int trel = (tid >> 3) + rr * 32;
      if (trel < 132) {
        int tp = fb + trel;
        float va[8];
        if ((unsigned)tp < 1024u) {
          const float4* src = (const float4*)(xbh + (size_t)tp * 64 + fi0);
          float4 u0 = src[0], u1 = src[1];
          va[0] = u0.x; va[1] = u0.y; va[2] = u0.z; va[3] = u0.w;
          va[4] = u1.x; va[5] = u1.y; va[6] = u1.z; va[7] = u1.w;
        } else {
#pragma unroll
          for (int j = 0; j < 8; ++j) va[j] = 0.f;
        }
        bhalf8 pk;
#pragma unroll
        for (int j = 0; j < 8; ++j) pk[j] = (short)f2bf(va[j]);
        *(bhalf8*)((char*)farw + (trel << 7) +
                   ((fi0 * 2) ^ ((trel & 7) << 4))) = pk;
      }
    }
    // ---- stage all 9 W tiles (16B/thread/half, conflict-free stride-16B)
#pragma unroll
    for (int d = 0; d < 9; ++d) {
      const char* src = (const char*)wt_img + (size_t)d * 8192;
      char* dst = (char*)wl + (size_t)d * 8192;
      *(bhalf8*)(dst + tid * 16) = *(const bhalf8*)(src + tid * 16);
      *(bhalf8*)(dst + 4096 + tid * 16) =
          *(const bhalf8*)(src + 4096 + tid * 16);
    }
  }
  __syncthreads();  // the only barrier

  const int l15 = tid & 15;
  const int l4 = (tid >> 4) & 3;
  const int wid = tid >> 6;
  const int wm = wid * 32;
  const int vdi = (t0 < 512) ? 2 : 0;

  // per-(kp,mt) column coords for j'-validity masks (static-indexed)
  const int rt0 = t0 + wm + l15, rt1 = rt0 + 16;
  int jma[NF], jmb[NF];
  jma[0] = rt0 & 511;  jmb[0] = rt1 & 511;
  jma[1] = rt0 % 10;   jmb[1] = rt1 % 10;
  jma[2] = rt0 % 5;    jmb[2] = rt1 % 5;
  jma[3] = rt0 % 4;    jmb[3] = rt1 % 4;
  jma[4] = rt0 % 3;    jmb[4] = rt1 % 3;
  jma[5] = rt0 & 1;    jmb[5] = rt1 & 1;

  floatx4 acc[NF][2][4];
#pragma unroll
  for (int kp = 0; kp < NF; ++kp)
#pragma unroll
    for (int mt = 0; mt < 2; ++mt)
#pragma unroll
      for (int nt = 0; nt < 4; ++nt) acc[kp][mt][nt] = (floatx4)0.0f;

  const bhalf8 zz = (bhalf8)0;

#define DO_TAP(KP, BUF, R0, Q)                                                \
  {                                                                           \
    bool ok0 = (dj == 0) ? (jma[KP] > 0)                                      \
               : (dj == 2) ? (jma[KP] < (Q) - 1) : true;                      \
    bool ok1 = (dj == 0) ? (jmb[KP] > 0)                                      \
               : (dj == 2) ? (jmb[KP] < (Q) - 1) : true;                      \
    int r0_ = (R0), r1_ = r0_ + 16;                                           \
    _Pragma("unroll") for (int kk = 0; kk < 2; ++kk) {                        \
      int kb = kk * 64 + l4 * 16;                                             \
      bhalf8 a0 = *(const bhalf8*)((const char*)(BUF) + (r0_ << 7) +          \
                                   (kb ^ ((r0_ & 7) << 4)));                  \
      bhalf8 a1 = *(const bhalf8*)((const char*)(BUF) + (r1_ << 7) +          \
                                   (kb ^ ((r1_ & 7) << 4)));                  \
      if (!ok0) a0 = zz;                                                      \
      if (!ok1) a1 = zz;                                                      \
      _Pragma("unroll") for (int nt = 0; nt < 4; ++nt) {                      \
        acc[KP][0][nt] = __builtin_amdgcn_mfma_f32_16x16x32_bf16(             \
            a0, bfr[kk][nt], acc[KP][0][nt], 0, 0, 0);                        \
        acc[KP][1][nt] = __builtin_amdgcn_mfma_f32_16x16x32_bf16(             \
            a1, bfr[kk][nt], acc[KP][1][nt], 0, 0, 0);                        \
      }                                                                       \
    }                                                                         \
  }

#pragma unroll
  for (int di = 0; di < 3; ++di) {
#pragma unroll
    for (int dj = 0; dj < 3; ++dj) {
      // B-fragments for this tap, reused by all 6 periods
      bhalf8 bfr[2][4];
      const char* wt = (const char*)wl + (size_t)(di * 3 + dj) * 8192;
#pragma unroll
      for (int kk = 0; kk < 2; ++kk)
#pragma unroll
        for (int nt = 0; nt < 4; ++nt) {
          int fo = nt * 16 + l15;
          bfr[kk][nt] = *(const bhalf8*)(wt + (fo << 7) +
                                         ((kk * 64 + l4 * 16) ^
                                          ((fo & 7) << 4)));
        }
      const int base = wm + l15;
      // kp = 0 (q = 512): center di from win, valid far di from farw
      if (di == 1) {
        DO_TAP(0, win, base + 11 + dj, 512)
      } else if (di == vdi) {
        DO_TAP(0, farw, base + dj + 1, 512)
      }
      DO_TAP(1, win, base + 12 + (di - 1) * 10 + dj - 1, 10)
      DO_TAP(2, win, base + 12 + (di - 1) * 5 + dj - 1, 5)
      DO_TAP(3, win, base + 12 + (di - 1) * 4 + dj - 1, 4)
      DO_TAP(4, win, base + 12 + (di - 1) * 3 + dj - 1, 3)
      DO_TAP(5, win, base + 12 + (di - 1) * 2 + dj - 1, 2)
    }
  }
#undef DO_TAP

  // epilogue: out = sum_kp pw[kp]*relu(acc[kp]+b) + x
  float pwv[NF];
#pragma unroll
  for (int kp = 0; kp < NF; ++kp) pwv[kp] = pwbuf[bh * NF + kp];
  float bv[4];
#pragma unroll
  for (int nt = 0; nt < 4; ++nt) bv[nt] = bias[nt * 16 + l15];

#pragma unroll
  for (int mt = 0; mt < 2; ++mt) {
#pragma unroll
    for (int nt = 0; nt < 4; ++nt) {
      int row = t0 + wm + mt * 16 + l4 * 4;
      int col = nt * 16 + l15;
      size_t basep = ((size_t)bh * 1024 + row) * 64 + col;
#pragma unroll
      for (int r = 0; r < 4; ++r) {
        float y = 0.f;
#pragma unroll
        for (int kp = 0; kp < NF; ++kp)
          y = fmaf(pwv[kp], fmaxf(acc[kp][mt][nt][r] + bv[nt], 0.f), y);
        out[basep + (size_t)r * 64] = y + x[basep + (size_t)r * 64];
      }
    }
  }
}

extern "C" void kernel_launch(void* const* d_in, const int* in_sizes, int n_in,
                              void* d_out, int out_size, void* d_ws,
                              size_t ws_size, hipStream_t stream) {
  const float* x = (const float*)d_in[0];
  const float* W = (const float*)d_in[1];
  const float* b = (const float*)d_in[2];
  float* out = (float*)d_out;
  float* pwbuf = (float*)d_ws;                                    // 6144 B
  unsigned short* wt_img = (unsigned short*)((char*)d_ws + 8192); // 73728 B

  pw_kernel<<<dim3(256), dim3(256), 0, stream>>>(x, pwbuf);
  prep_w<<<dim3(18), dim3(256), 0, stream>>>(W, wt_img);
  conv_kernel<<<dim3(8, 256), dim3(256), 0, stream>>>(x, wt_img, b, pwbuf, out);
}